// Round 3
// baseline (5036.169 us; speedup 1.0000x reference)
//
#include <hip/hip_runtime.h>
#include <cstdint>

#define BATCH 64
#define SEQ   1024
#define FEAT  16
#define HID   256
#define GATE  768   // 3*HID
#define TC    128   // time-chunk length
#define TCSH  7     // log2(TC)
#define NT    512   // gru block threads (8 waves)

typedef _Float16 h2 __attribute__((ext_vector_type(2)));

__device__ __forceinline__ float dot2f(float a, float b, float c) {
    return __builtin_amdgcn_fdot2(__builtin_bit_cast(h2, a),
                                  __builtin_bit_cast(h2, b), c, false);
}
__device__ __forceinline__ float sigmoidf_(float x) { return 1.0f / (1.0f + __expf(-x)); }
__device__ __forceinline__ float tanhf_(float x)    { return 2.0f / (1.0f + __expf(-2.0f * x)) - 1.0f; }

// ---------------------------------------------------------------------------
// Pack U (fp32 [HID][GATE]) -> Upk (f16x2 dwords, [GATE][HID/2]):
// Upk[c][kk] = (half(U[2kk][c]), half(U[2kk+1][c]))
// ---------------------------------------------------------------------------
__global__ __launch_bounds__(256) void k_packU(const float* __restrict__ U,
                                               float* __restrict__ Upk)
{
    const int idx = blockIdx.x * 256 + threadIdx.x;   // < GATE * 128
    const int c  = idx >> 7;
    const int kk = idx & 127;
    h2 v;
    v.x = (_Float16)U[(size_t)(2 * kk)     * GATE + c];
    v.y = (_Float16)U[(size_t)(2 * kk + 1) * GATE + c];
    Upk[idx] = __builtin_bit_cast(float, v);
}

// ---------------------------------------------------------------------------
// Layer-0 input projection
// ---------------------------------------------------------------------------
__global__ __launch_bounds__(256) void k_xp0(
    const int* __restrict__ batch, const float* __restrict__ W0,
    const float* __restrict__ b0, float* __restrict__ xp, int t0)
{
    const int r   = blockIdx.x;                       // 0 .. BATCH*TC-1
    const int col = blockIdx.y * 256 + threadIdx.x;   // 0 .. GATE-1
    const int b   = r >> TCSH;
    const int tl  = r & (TC - 1);
    const int* x = batch + ((size_t)b * SEQ + t0 + tl) * FEAT;
    float acc = b0[col];
#pragma unroll
    for (int f = 0; f < FEAT; ++f)
        acc += (float)x[f] * W0[f * GATE + col];
    xp[(size_t)r * GATE + col] = acc;
}

// ---------------------------------------------------------------------------
// Layers 1/2 input projection GEMM (64x128 tile, K-step 16)
// ---------------------------------------------------------------------------
#define BM 64
#define BN 128
#define BK 16

__global__ __launch_bounds__(256) void k_gemm(
    const float* __restrict__ Y, const float* __restrict__ W,
    const float* __restrict__ b0, float* __restrict__ xp, int t0)
{
    __shared__ float As[BK][BM + 4];
    __shared__ float Bs[BK][BN];

    const int m0 = blockIdx.x * BM;
    const int n0 = blockIdx.y * BN;
    const int tid = threadIdx.x;
    const int tx = tid & 31;
    const int ty = tid >> 5;
    const int ar = tid >> 2;
    const int ac = (tid & 3) * 4;
    const int kr = tid >> 4;
    const int bc = (tid & 15) * 8;

    float acc[8][4] = {};

    for (int k0 = 0; k0 < HID; k0 += BK) {
        {
            const int r  = m0 + ar;
            const int b  = r >> TCSH;
            const int tl = r & (TC - 1);
            float4 av = *(const float4*)(Y + ((size_t)b * SEQ + t0 + tl) * HID + k0 + ac);
            As[ac + 0][ar] = av.x; As[ac + 1][ar] = av.y;
            As[ac + 2][ar] = av.z; As[ac + 3][ar] = av.w;
            float4 bv0 = *(const float4*)(W + (size_t)(k0 + kr) * GATE + n0 + bc);
            float4 bv1 = *(const float4*)(W + (size_t)(k0 + kr) * GATE + n0 + bc + 4);
            *(float4*)&Bs[kr][bc]     = bv0;
            *(float4*)&Bs[kr][bc + 4] = bv1;
        }
        __syncthreads();
#pragma unroll
        for (int k = 0; k < BK; ++k) {
            float4 a0 = *(const float4*)&As[k][ty * 8];
            float4 a1 = *(const float4*)&As[k][ty * 8 + 4];
            float4 bv = *(const float4*)&Bs[k][tx * 4];
            float av_[8] = {a0.x, a0.y, a0.z, a0.w, a1.x, a1.y, a1.z, a1.w};
            float bv_[4] = {bv.x, bv.y, bv.z, bv.w};
#pragma unroll
            for (int i = 0; i < 8; ++i)
#pragma unroll
                for (int j = 0; j < 4; ++j)
                    acc[i][j] += av_[i] * bv_[j];
        }
        __syncthreads();
    }

#pragma unroll
    for (int i = 0; i < 8; ++i) {
        const int r = m0 + ty * 8 + i;
        float* crow = xp + (size_t)r * GATE + n0 + tx * 4;
#pragma unroll
        for (int j = 0; j < 4; ++j)
            crow[j] = acc[i][j] + b0[n0 + tx * 4 + j];
    }
}

// ---------------------------------------------------------------------------
// GRU recurrence. 512 threads (8 waves). Thread (w,l): quad q=l>>2, sub=l&3.
// Matvec cols c0..c0+5, c0 = w*96 + q*6; k-dwords [sub*32, sub*32+32).
// U fragment: 192 VGPRs. h stored f16-packed in 4 chunks of 128B at stride
// 144B (bank-quad swizzle -> conflict-free b128 reads).
// k-split-4 reduced via shfl_xor(1),shfl_xor(2); gates on ALL threads
// (columns duplicated x2), recurrent bias added in gate phase.
// ---------------------------------------------------------------------------
__global__ __launch_bounds__(NT, 2) void k_gru(
    const float* __restrict__ xp, const float* __restrict__ Upk,
    const float* __restrict__ b1, const int* __restrict__ batch,
    float* __restrict__ out, float* __restrict__ hfinal,
    float* __restrict__ hstate, int t0)
{
    __shared__ __align__(16) char hswz[4 * 144];   // 4 chunks x 128B used, 144B stride
    __shared__ float rec[GATE];

    const int b    = blockIdx.x;
    const int T    = threadIdx.x;
    const int w    = T >> 6;        // wave 0..7
    const int l    = T & 63;
    const int sub  = l & 3;         // k-split part
    const int quad = l >> 2;        // 0..15
    const int c0   = w * 96 + quad * 6;   // 6 matvec columns
    const int cg   = T & 255;             // gate column (x2 duplicated)

    // ---- load U fragment: 6 cols x 32 dwords = 192 VGPRs ----
    float u[192];
#pragma unroll
    for (int ci = 0; ci < 6; ++ci) {
        const float4* src = (const float4*)(Upk + (size_t)(c0 + ci) * 128 + sub * 32);
#pragma unroll
        for (int i = 0; i < 8; ++i) {
            float4 v = src[i];
            u[ci * 32 + 4 * i + 0] = v.x;
            u[ci * 32 + 4 * i + 1] = v.y;
            u[ci * 32 + 4 * i + 2] = v.z;
            u[ci * 32 + 4 * i + 3] = v.w;
        }
    }

    const float bz = b1[cg];
    const float br = b1[HID + cg];
    const float bh = b1[2 * HID + cg];

    // ---- init h ----
    float hprev = (t0 == 0) ? 0.0f : hstate[b * HID + cg];
    if (T < HID) {
        const int d = cg >> 1, q = d >> 5, wd = d & 31;
        *(_Float16*)(hswz + q * 144 + wd * 4 + (cg & 1) * 2) = (_Float16)hprev;
    }
    __syncthreads();

    const float4* h4 = (const float4*)(hswz + sub * 144);

    for (int tl = 0; tl < TC; ++tl) {
        const int t = t0 + tl;

        // prefetch xp row + mask (consumed after the matvec)
        const float* xrow = xp + ((size_t)b * TC + tl) * GATE;
        const float xz = xrow[cg];
        const float xr = xrow[HID + cg];
        const float xh = xrow[2 * HID + cg];
        const int mflag = batch[((size_t)b * SEQ + t) * FEAT + (FEAT - 1)];

        // ---- matvec partials: 6 cols x 32 dwords ----
        float a0 = 0.f, a1 = 0.f, a2 = 0.f, a3 = 0.f, a4 = 0.f, a5 = 0.f;
#pragma unroll
        for (int i = 0; i < 8; ++i) {
            float4 hv = h4[i];
            a0 = dot2f(hv.x, u[0 * 32 + 4 * i + 0], a0);
            a0 = dot2f(hv.y, u[0 * 32 + 4 * i + 1], a0);
            a0 = dot2f(hv.z, u[0 * 32 + 4 * i + 2], a0);
            a0 = dot2f(hv.w, u[0 * 32 + 4 * i + 3], a0);
            a1 = dot2f(hv.x, u[1 * 32 + 4 * i + 0], a1);
            a1 = dot2f(hv.y, u[1 * 32 + 4 * i + 1], a1);
            a1 = dot2f(hv.z, u[1 * 32 + 4 * i + 2], a1);
            a1 = dot2f(hv.w, u[1 * 32 + 4 * i + 3], a1);
            a2 = dot2f(hv.x, u[2 * 32 + 4 * i + 0], a2);
            a2 = dot2f(hv.y, u[2 * 32 + 4 * i + 1], a2);
            a2 = dot2f(hv.z, u[2 * 32 + 4 * i + 2], a2);
            a2 = dot2f(hv.w, u[2 * 32 + 4 * i + 3], a2);
            a3 = dot2f(hv.x, u[3 * 32 + 4 * i + 0], a3);
            a3 = dot2f(hv.y, u[3 * 32 + 4 * i + 1], a3);
            a3 = dot2f(hv.z, u[3 * 32 + 4 * i + 2], a3);
            a3 = dot2f(hv.w, u[3 * 32 + 4 * i + 3], a3);
            a4 = dot2f(hv.x, u[4 * 32 + 4 * i + 0], a4);
            a4 = dot2f(hv.y, u[4 * 32 + 4 * i + 1], a4);
            a4 = dot2f(hv.z, u[4 * 32 + 4 * i + 2], a4);
            a4 = dot2f(hv.w, u[4 * 32 + 4 * i + 3], a4);
            a5 = dot2f(hv.x, u[5 * 32 + 4 * i + 0], a5);
            a5 = dot2f(hv.y, u[5 * 32 + 4 * i + 1], a5);
            a5 = dot2f(hv.z, u[5 * 32 + 4 * i + 2], a5);
            a5 = dot2f(hv.w, u[5 * 32 + 4 * i + 3], a5);
        }

        // ---- butterfly reduce across k-split quad ----
        a0 += __shfl_xor(a0, 1, 64); a0 += __shfl_xor(a0, 2, 64);
        a1 += __shfl_xor(a1, 1, 64); a1 += __shfl_xor(a1, 2, 64);
        a2 += __shfl_xor(a2, 1, 64); a2 += __shfl_xor(a2, 2, 64);
        a3 += __shfl_xor(a3, 1, 64); a3 += __shfl_xor(a3, 2, 64);
        a4 += __shfl_xor(a4, 1, 64); a4 += __shfl_xor(a4, 2, 64);
        a5 += __shfl_xor(a5, 1, 64); a5 += __shfl_xor(a5, 2, 64);

        // sub 0 writes cols c0..c0+2, sub 1 writes c0+3..c0+5
        {
            const float w0 = (sub & 1) ? a3 : a0;
            const float w1 = (sub & 1) ? a4 : a1;
            const float w2 = (sub & 1) ? a5 : a2;
            if (sub < 2) {
                const int cb = c0 + 3 * sub;
                rec[cb + 0] = w0;
                rec[cb + 1] = w1;
                rec[cb + 2] = w2;
            }
        }
        __syncthreads();

        // ---- gates on all threads (2x duplicated per column) ----
        {
            const float rz = rec[cg];
            const float rr = rec[HID + cg];
            const float rh = rec[2 * HID + cg];
            const float z  = sigmoidf_(xz + rz + bz);
            const float r  = sigmoidf_(xr + rr + br);
            const float hh = tanhf_(xh + r * (rh + bh));
            float hn = z * hprev + (1.0f - z) * hh;
            hn = (mflag != -1) ? hn : hprev;
            hprev = hn;
            if (T < HID) {
                out[((size_t)b * SEQ + t) * HID + cg] = hn;
                const int d = cg >> 1, q = d >> 5, wd = d & 31;
                *(_Float16*)(hswz + q * 144 + wd * 4 + (cg & 1) * 2) = (_Float16)hn;
            }
        }
        __syncthreads();
    }

    if (T < HID) {
        hstate[b * HID + cg] = hprev;
        if (hfinal) hfinal[b * HID + cg] = hprev;
    }
}

// ---------------------------------------------------------------------------
extern "C" void kernel_launch(void* const* d_in, const int* in_sizes, int n_in,
                              void* d_out, int out_size, void* d_ws, size_t ws_size,
                              hipStream_t stream)
{
    const int*   batch = (const int*)d_in[0];
    const float* W0 = (const float*)d_in[1];
    const float* U0 = (const float*)d_in[2];
    const float* b0 = (const float*)d_in[3];
    const float* W1 = (const float*)d_in[4];
    const float* U1 = (const float*)d_in[5];
    const float* b1 = (const float*)d_in[6];
    const float* W2 = (const float*)d_in[7];
    const float* U2 = (const float*)d_in[8];
    const float* b2 = (const float*)d_in[9];

    float* out  = (float*)d_out;
    float* hfin = out + (size_t)BATCH * SEQ * HID;

    // ws layout: xp chunk | y | hstate | Upk0 | Upk1 | Upk2
    float* xp     = (float*)d_ws;
    float* y      = xp + (size_t)BATCH * TC * GATE;
    float* hstate = y + (size_t)BATCH * SEQ * HID;
    float* Upk0   = hstate + (size_t)BATCH * HID;
    float* Upk1   = Upk0 + (size_t)GATE * 128;
    float* Upk2   = Upk1 + (size_t)GATE * 128;

    dim3 gpack(GATE * 128 / 256), bpack(256);
    dim3 gxp0(BATCH * TC, 3), bxp0(256);
    dim3 ggemm(BATCH * TC / BM, GATE / BN), bgemm(256);
    dim3 ggru(BATCH), bgru(NT);

    k_packU<<<gpack, bpack, 0, stream>>>(U0, Upk0);
    k_packU<<<gpack, bpack, 0, stream>>>(U1, Upk1);
    k_packU<<<gpack, bpack, 0, stream>>>(U2, Upk2);

    // ----- layer 0 -----
    for (int t0 = 0; t0 < SEQ; t0 += TC) {
        k_xp0<<<gxp0, bxp0, 0, stream>>>(batch, W0, b0, xp, t0);
        k_gru<<<ggru, bgru, 0, stream>>>(xp, Upk0, b0 + GATE, batch, y, nullptr, hstate, t0);
    }
    // ----- layer 1 -----
    for (int t0 = 0; t0 < SEQ; t0 += TC) {
        k_gemm<<<ggemm, bgemm, 0, stream>>>(y, W1, b1, xp, t0);
        k_gru<<<ggru, bgru, 0, stream>>>(xp, Upk1, b1 + GATE, batch, y, nullptr, hstate, t0);
    }
    // ----- layer 2 -----
    for (int t0 = 0; t0 < SEQ; t0 += TC) {
        k_gemm<<<ggemm, bgemm, 0, stream>>>(y, W2, b2, xp, t0);
        k_gru<<<ggru, bgru, 0, stream>>>(xp, Upk2, b2 + GATE, batch, out,
                                         (t0 + TC == SEQ) ? hfin : nullptr, hstate, t0);
    }
}